// Round 10
// baseline (159.008 us; speedup 1.0000x reference)
//
#include <hip/hip_runtime.h>
#include <hip/hip_bf16.h>

#define CIN 256
#define CRED 64
#define NB 4
#define NN 4096

typedef float v4f __attribute__((ext_vector_type(4)));
typedef short v8s __attribute__((ext_vector_type(8)));
typedef unsigned short u16;
typedef u16 u16x4 __attribute__((ext_vector_type(4)));
typedef u16 u16x8 __attribute__((ext_vector_type(8)));
typedef unsigned int u32;

#define LOG2E 1.4426950408889634f

__device__ __forceinline__ u16 f2bf(float f) {
    union { float f; u32 u; } v; v.f = f;
    u32 r = (v.u + 0x7FFFu + ((v.u >> 16) & 1u)) >> 16;  // RNE
    return (u16)r;
}
__device__ __forceinline__ float bf2f(u16 s) {
    union { u32 u; float f; } v; v.u = ((u32)s) << 16;
    return v.f;
}
// packed f32x2 -> bf16x2 (v_cvt_pk_bf16_f32 on gfx950), low half = a
__device__ __forceinline__ u32 pkbf(float a, float b) {
    float2 f; f.x = a; f.y = b;
    __hip_bfloat162 h = __float22bfloat162_rn(f);
    union { __hip_bfloat162 h; u32 u; } c; c.h = h;
    return c.u;
}
__device__ __forceinline__ v4f mfma16(v8s a, v8s b, v4f c) {
    return __builtin_amdgcn_mfma_f32_16x16x32_bf16(a, b, c, 0, 0, 0);
}
__device__ __forceinline__ float fexp2(float x) {
#if __has_builtin(__builtin_amdgcn_exp2f)
    return __builtin_amdgcn_exp2f(x);
#else
    return exp2f(x);
#endif
}

// ------------- kernel 1: QKV via MFMA, all 3 mats per block (x read once) ---
// Q,K: (b,n,r) bf16 (Q scaled 0.125*log2e). V: (b,r,n) with key-permuted n
// inside each 64-tile: pos(n) = (n&15)*4 + ((n>>4)&3). W converted inline.
__global__ __launch_bounds__(256) void k_qkvm(const float* __restrict__ x,
                                              const float* __restrict__ Wq,
                                              const float* __restrict__ Wk,
                                              const float* __restrict__ Wv,
                                              u16* __restrict__ Q, u16* __restrict__ K,
                                              u16* __restrict__ V) {
    int t = threadIdx.x;
    int wv = t >> 6, lane = t & 63, c15 = lane & 15, quad = lane >> 4;
    int n0g = blockIdx.x * 32;
    int b = n0g >> 12, nb = n0g & 4095;
    const float* xb = x + ((size_t)b << 20);

    // A-frags straight from global: A[m=n_local][k=c]
    v8s Af[2][8];
#pragma unroll
    for (int nt = 0; nt < 2; ++nt) {
        const float* px = xb + nb + nt * 16 + c15 + (size_t)quad * 8 * 4096;
#pragma unroll
        for (int kc = 0; kc < 8; ++kc) {
            float f[8];
#pragma unroll
            for (int j = 0; j < 8; ++j)
                f[j] = px[((size_t)kc * 32 + j) * 4096];
            union { v8s s; u32 w[4]; } pk;
            pk.w[0] = pkbf(f[0], f[1]); pk.w[1] = pkbf(f[2], f[3]);
            pk.w[2] = pkbf(f[4], f[5]); pk.w[3] = pkbf(f[6], f[7]);
            Af[nt][kc] = pk.s;
        }
    }

    // wave wv -> output r-tiles 3wv..3wv+2 (0-3 Q, 4-7 K, 8-11 V)
#pragma unroll
    for (int rti = 0; rti < 3; ++rti) {
        int rt = wv * 3 + rti;
        const float* W = (rt < 4) ? Wq : (rt < 8) ? Wk : Wv;
        float s = (rt < 4) ? (0.125f * LOG2E) : 1.0f;
        const float* wr = W + (size_t)((rt & 3) * 16 + c15) * 256 + quad * 8;
        v8s Bf[8];
#pragma unroll
        for (int kc = 0; kc < 8; ++kc) {
            float4 a = *(const float4*)&wr[kc * 32];
            float4 c = *(const float4*)&wr[kc * 32 + 4];
            union { v8s s; u32 w[4]; } pk;
            pk.w[0] = pkbf(a.x * s, a.y * s); pk.w[1] = pkbf(a.z * s, a.w * s);
            pk.w[2] = pkbf(c.x * s, c.y * s); pk.w[3] = pkbf(c.z * s, c.w * s);
            Bf[kc] = pk.s;
        }
#pragma unroll
        for (int nt = 0; nt < 2; ++nt) {
            v4f acc = {0.f, 0.f, 0.f, 0.f};
#pragma unroll
            for (int kc = 0; kc < 8; ++kc)
                acc = mfma16(Af[nt][kc], Bf[kc], acc);
            // C layout: row(n_local) = quad*4+g, col(r_local) = c15
            if (rt < 8) {
                u16* base = (rt < 4) ? Q : K;
                u16* dst = base + ((size_t)b << 18)
                         + (size_t)(nb + nt * 16 + quad * 4) * 64
                         + (rt & 3) * 16 + c15;
#pragma unroll
                for (int g = 0; g < 4; ++g) dst[g * 64] = f2bf(acc[g]);
            } else {
                // V permuted: n = nb+nt*16+quad*4+g ; pos=(n&15)*4+((n>>4)&3)
                int hi2 = ((nb + nt * 16) >> 4) & 3;
                size_t base = ((size_t)b * 64 + (rt - 8) * 16 + c15) * 4096
                            + (size_t)((nb + nt * 16) & ~63) + hi2;
#pragma unroll
                for (int g = 0; g < 4; ++g)
                    V[base + (quad * 4 + g) * 4] = f2bf(acc[g]);
            }
        }
    }
}

// ------------- kernel 2: flash attention -------------------------------------
// K LDS double-buffered (shared x4 waves), V direct from global/L2,
// one barrier per iter with nothing outstanding at it; 4 blocks/CU.
__global__ __launch_bounds__(256, 4) void k_flash(const u16* __restrict__ Q,
                                                  const u16* __restrict__ K,
                                                  const u16* __restrict__ V,
                                                  u16* __restrict__ OP,
                                                  float* __restrict__ Lb,
                                                  int sh) {
    __shared__ u16 Kl[2][64][72];    // K tile (m,r), double-buffered (18.4 KB)
    __shared__ u16 Pl[4][32][72];    // per-wave P: [row][pos] (18.4 KB)
    int t = threadIdx.x;
    int p = blockIdx.x & ((1u << sh) - 1);
    int tile = blockIdx.x >> sh;
    int b = tile >> 5;
    int n0 = (tile & 31) * 128;
    int wv = t >> 6;
    int lane = t & 63;
    int c15 = lane & 15;
    int quad = lane >> 4;
    int nw = n0 + wv * 32;
    const u16* Qb = Q + (size_t)b * NN * 64;
    const u16* Kb = K + (size_t)b * NN * 64;
    const u16* Vb = V + (size_t)b * 64 * NN;

    v8s Qa[2][2];
#pragma unroll
    for (int rg = 0; rg < 2; ++rg)
#pragma unroll
        for (int c2 = 0; c2 < 2; ++c2)
            Qa[rg][c2] = *(const v8s*)&Qb[(size_t)(nw + rg * 16 + c15) * 64 + c2 * 32 + quad * 8];

    v4f O[2][4];
    float ls[2][4];
#pragma unroll
    for (int rg = 0; rg < 2; ++rg)
#pragma unroll
        for (int g = 0; g < 4; ++g) {
            ls[rg][g] = 0.f;
#pragma unroll
            for (int cg = 0; cg < 4; ++cg) O[rg][cg][g] = 0.f;
        }

    int mlen = NN >> sh;
    int m0 = p * mlen;
    int iters = mlen >> 6;
    int srow = t >> 3, scol = (t & 7) * 8;

    // stage K tile 0 into buffer 0
#pragma unroll
    for (int pass = 0; pass < 2; ++pass) {
        int rr = srow + pass * 32;
        *(v8s*)&Kl[0][rr][scol] = *(const v8s*)&Kb[(size_t)(m0 + rr) * 64 + scol];
    }
    __syncthreads();

    for (int it = 0; it < iters; ++it) {
        int cur = it & 1, nxt = cur ^ 1;
        int mt = m0 + it * 64;

        // K prefetch for it+1 (consumed by LDS commit before the barrier)
        v8s kn[2];
        if (it + 1 < iters) {
            int mt1 = mt + 64;
#pragma unroll
            for (int pass = 0; pass < 2; ++pass) {
                int rr = srow + pass * 32;
                kn[pass] = *(const v8s*)&Kb[(size_t)(mt1 + rr) * 64 + scol];
            }
        }
        // V direct loads, first half (cg 0,1) — latency covered by S+softmax
        v8s vd0[2][2];
#pragma unroll
        for (int cg = 0; cg < 2; ++cg)
#pragma unroll
            for (int c2 = 0; c2 < 2; ++c2)
                vd0[cg][c2] = *(const v8s*)&Vb[(size_t)(cg * 16 + c15) * NN + mt + c2 * 32 + quad * 8];

        v4f S[2][4];
#pragma unroll
        for (int rg = 0; rg < 2; ++rg)
#pragma unroll
            for (int s = 0; s < 4; ++s)
#pragma unroll
                for (int g = 0; g < 4; ++g) S[rg][s][g] = 0.f;
#pragma unroll
        for (int s = 0; s < 4; ++s)
#pragma unroll
            for (int c2 = 0; c2 < 2; ++c2) {
                v8s kb = *(const v8s*)&Kl[cur][s * 16 + c15][c2 * 32 + quad * 8];
                S[0][s] = mfma16(Qa[0][c2], kb, S[0][s]);
                S[1][s] = mfma16(Qa[1][c2], kb, S[1][s]);
            }

        // V direct loads, second half (cg 2,3)
        v8s vd1[2][2];
#pragma unroll
        for (int cg = 0; cg < 2; ++cg)
#pragma unroll
            for (int c2 = 0; c2 < 2; ++c2)
                vd1[cg][c2] = *(const v8s*)&Vb[(size_t)((cg + 2) * 16 + c15) * NN + mt + c2 * 32 + quad * 8];

        // fixed-max softmax: P = 2^s ; packed writes to permuted columns
#pragma unroll
        for (int rg = 0; rg < 2; ++rg) {
            float E[4][4];
#pragma unroll
            for (int s = 0; s < 4; ++s)
#pragma unroll
                for (int g = 0; g < 4; ++g) {
                    float e = fexp2(S[rg][s][g]);
                    E[s][g] = e;
                    ls[rg][g] += e;
                }
#pragma unroll
            for (int g = 0; g < 4; ++g) {
                union { u16x4 v; u32 w[2]; } p2;
                p2.w[0] = pkbf(E[0][g], E[1][g]);
                p2.w[1] = pkbf(E[2][g], E[3][g]);
                *(u16x4*)&Pl[wv][rg * 16 + quad * 4 + g][c15 * 4] = p2.v;
            }
        }
        // per-wave LDS round-trip: lgkmcnt orders intra-wave, no barrier

        v8s Pa[2][2];
#pragma unroll
        for (int rg = 0; rg < 2; ++rg)
#pragma unroll
            for (int c2 = 0; c2 < 2; ++c2)
                Pa[rg][c2] = *(const v8s*)&Pl[wv][rg * 16 + c15][c2 * 32 + quad * 8];
#pragma unroll
        for (int cg = 0; cg < 2; ++cg)
#pragma unroll
            for (int c2 = 0; c2 < 2; ++c2) {
                O[0][cg] = mfma16(Pa[0][c2], vd0[cg][c2], O[0][cg]);
                O[1][cg] = mfma16(Pa[1][c2], vd0[cg][c2], O[1][cg]);
                O[0][cg + 2] = mfma16(Pa[0][c2], vd1[cg][c2], O[0][cg + 2]);
                O[1][cg + 2] = mfma16(Pa[1][c2], vd1[cg][c2], O[1][cg + 2]);
            }

        // commit next K tile to the idle buffer, then ONE barrier (no drain)
        if (it + 1 < iters) {
#pragma unroll
            for (int pass = 0; pass < 2; ++pass) {
                int rr = srow + pass * 32;
                *(v8s*)&Kl[nxt][rr][scol] = kn[pass];
            }
        }
        __syncthreads();
    }

    u16* OPp = OP + (size_t)p * (NB * NN * 64) + (size_t)b * NN * 64;
#pragma unroll
    for (int rg = 0; rg < 2; ++rg)
#pragma unroll
        for (int cg = 0; cg < 4; ++cg)
#pragma unroll
            for (int g = 0; g < 4; ++g) {
                int n = nw + rg * 16 + quad * 4 + g;
                OPp[(size_t)n * 64 + cg * 16 + c15] = f2bf(O[rg][cg][g]);
            }
#pragma unroll
    for (int rg = 0; rg < 2; ++rg)
#pragma unroll
        for (int g = 0; g < 4; ++g) {
            float v = ls[rg][g];
#pragma unroll
            for (int off = 1; off <= 8; off <<= 1) v += __shfl_xor(v, off);
            ls[rg][g] = v;
        }
    if (c15 == 0) {
        float* Lp = Lb + (size_t)p * (NB * NN) + (size_t)b * NN;
#pragma unroll
        for (int rg = 0; rg < 2; ++rg)
#pragma unroll
            for (int g = 0; g < 4; ++g) {
                int n = nw + rg * 16 + quad * 4 + g;
                Lp[n] = ls[rg][g];
            }
    }
}

// ------------- kernel 3: merge splits + Wp MFMA projection + residual -------
#define OMP 72
__global__ __launch_bounds__(256) void k_proj(const u16* __restrict__ OP,
                                              const float* __restrict__ Lb,
                                              const float* __restrict__ Wp,
                                              const float* __restrict__ x,
                                              float* __restrict__ out,
                                              int nsp) {
    __shared__ u16 Om[16 * OMP];
    int t = threadIdx.x;
    int b = blockIdx.x >> 8;
    int n0 = (blockIdx.x & 255) * 16;

    {
        int n_l = t >> 4, r0 = (t & 15) * 4;
        size_t nidx = (size_t)b * NN + n0 + n_l;
        float o[4] = {0.f, 0.f, 0.f, 0.f};
        float l = 0.f;
        for (int p = 0; p < nsp; ++p) {
            u16x4 u = *(const u16x4*)&OP[((size_t)p * (NB * NN) + nidx) * 64 + r0];
#pragma unroll
            for (int j = 0; j < 4; ++j) o[j] += bf2f(u[j]);
            l += Lb[(size_t)p * (NB * NN) + nidx];
        }
        float inv = 1.0f / l;
        union { u16x4 v; u32 w[2]; } p2;
        p2.w[0] = pkbf(o[0] * inv, o[1] * inv);
        p2.w[1] = pkbf(o[2] * inv, o[3] * inv);
        *(u16x4*)&Om[n_l * OMP + r0] = p2.v;
    }
    __syncthreads();

    int lane = t & 63, wvv = t >> 6, c15 = lane & 15, quad = lane >> 4;
    v8s B0 = *(const v8s*)&Om[c15 * OMP + quad * 8];
    v8s B1 = *(const v8s*)&Om[c15 * OMP + 32 + quad * 8];
#pragma unroll
    for (int ct0 = 0; ct0 < 4; ++ct0) {
        int ct = wvv * 4 + ct0;
        // inline fp32 Wp -> bf16 A-frags: A[m=cout][k=r]
        const float* wr = Wp + (size_t)(ct * 16 + c15) * 64 + quad * 8;
        float4 wa = *(const float4*)&wr[0];
        float4 wb = *(const float4*)&wr[4];
        float4 wc = *(const float4*)&wr[32];
        float4 wd = *(const float4*)&wr[36];
        union { v8s s; u32 w[4]; } pa, pb;
        pa.w[0] = pkbf(wa.x, wa.y); pa.w[1] = pkbf(wa.z, wa.w);
        pa.w[2] = pkbf(wb.x, wb.y); pa.w[3] = pkbf(wb.z, wb.w);
        pb.w[0] = pkbf(wc.x, wc.y); pb.w[1] = pkbf(wc.z, wc.w);
        pb.w[2] = pkbf(wd.x, wd.y); pb.w[3] = pkbf(wd.z, wd.w);
        v4f acc = {0.f, 0.f, 0.f, 0.f};
        acc = mfma16(pa.s, B0, acc);
        acc = mfma16(pb.s, B1, acc);
        size_t base = ((size_t)(b * 256 + ct * 16 + quad * 4)) * 4096 + n0 + c15;
#pragma unroll
        for (int g = 0; g < 4; ++g)
            out[base + (size_t)g * 4096] = acc[g] + x[base + (size_t)g * 4096];
    }
}

extern "C" void kernel_launch(void* const* d_in, const int* in_sizes, int n_in,
                              void* d_out, int out_size, void* d_ws, size_t ws_size,
                              hipStream_t stream) {
    const float* x  = (const float*)d_in[0];
    const float* Wq = (const float*)d_in[1];
    const float* Wk = (const float*)d_in[2];
    const float* Wv = (const float*)d_in[3];
    const float* Wp = (const float*)d_in[4];
    float* out = (float*)d_out;
    char* ws = (char*)d_ws;

    int nsp = (ws_size >= (size_t)24 * 1024 * 1024) ? 8 : 4;
    int sh = (nsp == 8) ? 3 : 2;

    u16* Q   = (u16*)(ws);                                   // 2 MB
    u16* K   = (u16*)(ws + 2097152);                         // 2 MB
    u16* V   = (u16*)(ws + 2 * 2097152);                     // 2 MB
    u16* OP  = (u16*)(ws + 3 * 2097152);                     // nsp*2 MB
    float* Lbuf = (float*)(ws + (size_t)(3 + nsp) * 2097152);

    k_qkvm<<<512, 256, 0, stream>>>(x, Wq, Wk, Wv, Q, K, V);
    k_flash<<<NB * 32 * nsp, 256, 0, stream>>>(Q, K, V, OP, Lbuf, sh);
    k_proj<<<NB * 256, 256, 0, stream>>>(OP, Lbuf, Wp, x, out, nsp);
}

// Round 11
// 130.386 us; speedup vs baseline: 1.2195x; 1.2195x over previous
//
#include <hip/hip_runtime.h>
#include <hip/hip_bf16.h>

#define CIN 256
#define CRED 64
#define NB 4
#define NN 4096

typedef float v4f __attribute__((ext_vector_type(4)));
typedef short v8s __attribute__((ext_vector_type(8)));
typedef unsigned short u16;
typedef u16 u16x4 __attribute__((ext_vector_type(4)));
typedef u16 u16x8 __attribute__((ext_vector_type(8)));
typedef unsigned int u32;

#define LOG2E 1.4426950408889634f

__device__ __forceinline__ u16 f2bf(float f) {
    union { float f; u32 u; } v; v.f = f;
    u32 r = (v.u + 0x7FFFu + ((v.u >> 16) & 1u)) >> 16;  // RNE
    return (u16)r;
}
__device__ __forceinline__ float bf2f(u16 s) {
    union { u32 u; float f; } v; v.u = ((u32)s) << 16;
    return v.f;
}
// packed f32x2 -> bf16x2 (v_cvt_pk_bf16_f32 on gfx950), low half = a
__device__ __forceinline__ u32 pkbf(float a, float b) {
    float2 f; f.x = a; f.y = b;
    __hip_bfloat162 h = __float22bfloat162_rn(f);
    union { __hip_bfloat162 h; u32 u; } c; c.h = h;
    return c.u;
}
__device__ __forceinline__ v4f mfma16(v8s a, v8s b, v4f c) {
    return __builtin_amdgcn_mfma_f32_16x16x32_bf16(a, b, c, 0, 0, 0);
}
__device__ __forceinline__ float fexp2(float x) {
#if __has_builtin(__builtin_amdgcn_exp2f)
    return __builtin_amdgcn_exp2f(x);
#else
    return exp2f(x);
#endif
}

// global -> LDS DMA, 16B per lane: lds dest = base + lane*16 (wave-uniform base)
__device__ __forceinline__ void dma16(const u16* g, u16* l) {
#if __has_builtin(__builtin_amdgcn_global_load_lds)
    __builtin_amdgcn_global_load_lds(
        (const __attribute__((address_space(1))) u32*)g,
        (__attribute__((address_space(3))) u32*)l, 16, 0, 0);
#else
    int lane = threadIdx.x & 63;
    *(v8s*)(l + lane * 8) = *(const v8s*)g;
#endif
}

// ------------- kernel 1: QKV via MFMA, all 3 mats per block (x read once) ---
// Q,K: (b,n,r) bf16 (Q scaled 0.125*log2e). V: (b,r,n) with key-permuted n
// inside each 64-tile: pos(n) = (n&15)*4 + ((n>>4)&3). W converted inline.
__global__ __launch_bounds__(256) void k_qkvm(const float* __restrict__ x,
                                              const float* __restrict__ Wq,
                                              const float* __restrict__ Wk,
                                              const float* __restrict__ Wv,
                                              u16* __restrict__ Q, u16* __restrict__ K,
                                              u16* __restrict__ V) {
    int t = threadIdx.x;
    int wv = t >> 6, lane = t & 63, c15 = lane & 15, quad = lane >> 4;
    int n0g = blockIdx.x * 32;
    int b = n0g >> 12, nb = n0g & 4095;
    const float* xb = x + ((size_t)b << 20);

    // A-frags straight from global: A[m=n_local][k=c]
    v8s Af[2][8];
#pragma unroll
    for (int nt = 0; nt < 2; ++nt) {
        const float* px = xb + nb + nt * 16 + c15 + (size_t)quad * 8 * 4096;
#pragma unroll
        for (int kc = 0; kc < 8; ++kc) {
            float f[8];
#pragma unroll
            for (int j = 0; j < 8; ++j)
                f[j] = px[((size_t)kc * 32 + j) * 4096];
            union { v8s s; u32 w[4]; } pk;
            pk.w[0] = pkbf(f[0], f[1]); pk.w[1] = pkbf(f[2], f[3]);
            pk.w[2] = pkbf(f[4], f[5]); pk.w[3] = pkbf(f[6], f[7]);
            Af[nt][kc] = pk.s;
        }
    }

    // wave wv -> output r-tiles 3wv..3wv+2 (0-3 Q, 4-7 K, 8-11 V)
#pragma unroll
    for (int rti = 0; rti < 3; ++rti) {
        int rt = wv * 3 + rti;
        const float* W = (rt < 4) ? Wq : (rt < 8) ? Wk : Wv;
        float s = (rt < 4) ? (0.125f * LOG2E) : 1.0f;
        const float* wr = W + (size_t)((rt & 3) * 16 + c15) * 256 + quad * 8;
        v8s Bf[8];
#pragma unroll
        for (int kc = 0; kc < 8; ++kc) {
            float4 a = *(const float4*)&wr[kc * 32];
            float4 c = *(const float4*)&wr[kc * 32 + 4];
            union { v8s s; u32 w[4]; } pk;
            pk.w[0] = pkbf(a.x * s, a.y * s); pk.w[1] = pkbf(a.z * s, a.w * s);
            pk.w[2] = pkbf(c.x * s, c.y * s); pk.w[3] = pkbf(c.z * s, c.w * s);
            Bf[kc] = pk.s;
        }
#pragma unroll
        for (int nt = 0; nt < 2; ++nt) {
            v4f acc = {0.f, 0.f, 0.f, 0.f};
#pragma unroll
            for (int kc = 0; kc < 8; ++kc)
                acc = mfma16(Af[nt][kc], Bf[kc], acc);
            // C layout: row(n_local) = quad*4+g, col(r_local) = c15
            if (rt < 8) {
                u16* base = (rt < 4) ? Q : K;
                u16* dst = base + ((size_t)b << 18)
                         + (size_t)(nb + nt * 16 + quad * 4) * 64
                         + (rt & 3) * 16 + c15;
#pragma unroll
                for (int g = 0; g < 4; ++g) dst[g * 64] = f2bf(acc[g]);
            } else {
                // V permuted: n = nb+nt*16+quad*4+g ; pos=(n&15)*4+((n>>4)&3)
                int hi2 = ((nb + nt * 16) >> 4) & 3;
                size_t base = ((size_t)b * 64 + (rt - 8) * 16 + c15) * 4096
                            + (size_t)((nb + nt * 16) & ~63) + hi2;
#pragma unroll
                for (int g = 0; g < 4; ++g)
                    V[base + (quad * 4 + g) * 4] = f2bf(acc[g]);
            }
        }
    }
}

// ------------- kernel 2: flash attention, DMA-staged, XOR-swizzled ----------
// LDS = Kl dbuf 16K + Vl 8K + Pl 16K = 40 KB exactly -> 4 blocks/CU.
// Per iter: DMA V(i) then K(i+1); S; softmax; waitcnt vmcnt(2)+raw barrier; PV;
// __syncthreads (auto-drain covers K(i+1), issued ~900cyc earlier).
__global__ __launch_bounds__(256, 4) void k_flash(const u16* __restrict__ Q,
                                                  const u16* __restrict__ K,
                                                  const u16* __restrict__ V,
                                                  u16* __restrict__ OP,
                                                  float* __restrict__ Lb,
                                                  int sh) {
    __shared__ u16 Kl[2][64][64];    // K tile (m, r-chunk^swz), dbuf
    __shared__ u16 Vl[64][64];       // V tile (r, pos-chunk^swz)
    __shared__ u16 Pl[4][32][64];    // per-wave P, chunk-swizzled
    int t = threadIdx.x;
    int p = blockIdx.x & ((1u << sh) - 1);
    int tile = blockIdx.x >> sh;
    int b = tile >> 5;
    int n0 = (tile & 31) * 128;
    int wv = t >> 6;
    int lane = t & 63;
    int c15 = lane & 15;
    int quad = lane >> 4;
    int nw = n0 + wv * 32;
    int l3 = lane >> 3, l7 = lane & 7;
    int swz = (l7 ^ l3) * 8;         // per-lane source chunk offset (u16 units)
    int r7 = c15 & 7;                // row&7 for rows ≡ c15 (mod 16)
    const u16* Qb = Q + (size_t)b * NN * 64;
    const u16* Kb = K + (size_t)b * NN * 64;
    const u16* Vb = V + (size_t)b * 64 * NN;

    v8s Qa[2][2];
#pragma unroll
    for (int rg = 0; rg < 2; ++rg)
#pragma unroll
        for (int c2 = 0; c2 < 2; ++c2)
            Qa[rg][c2] = *(const v8s*)&Qb[(size_t)(nw + rg * 16 + c15) * 64 + c2 * 32 + quad * 8];

    v4f O[2][4];
    float ls[2][4];
#pragma unroll
    for (int rg = 0; rg < 2; ++rg)
#pragma unroll
        for (int g = 0; g < 4; ++g) {
            ls[rg][g] = 0.f;
#pragma unroll
            for (int cg = 0; cg < 4; ++cg) O[rg][cg][g] = 0.f;
        }

    int mlen = NN >> sh;
    int m0 = p * mlen;
    int iters = mlen >> 6;

    // preload K tile 0 into buffer 0 (wave wv stages rows wv*16 .. +15)
#pragma unroll
    for (int j = 0; j < 2; ++j)
        dma16(&Kb[(size_t)(m0 + wv * 16 + j * 8 + l3) * 64 + swz],
              &Kl[0][wv * 16 + j * 8][0]);
    __syncthreads();

    for (int it = 0; it < iters; ++it) {
        int cur = it & 1, nxt = cur ^ 1;
        int mt = m0 + it * 64;
        int mt1 = m0 + ((it + 1) & (iters - 1)) * 64;  // wrap: always issue

        // V(i) first, then K(i+1): vmcnt(2) later waits V only
#pragma unroll
        for (int j = 0; j < 2; ++j)
            dma16(&Vb[(size_t)(wv * 16 + j * 8 + l3) * NN + mt + swz],
                  &Vl[wv * 16 + j * 8][0]);
#pragma unroll
        for (int j = 0; j < 2; ++j)
            dma16(&Kb[(size_t)(mt1 + wv * 16 + j * 8 + l3) * 64 + swz],
                  &Kl[nxt][wv * 16 + j * 8][0]);

        // S = Q K^T from Kl[cur] (swizzled chunks, 2-way bank = free)
        v4f S[2][4];
#pragma unroll
        for (int rg = 0; rg < 2; ++rg)
#pragma unroll
            for (int s = 0; s < 4; ++s)
#pragma unroll
                for (int g = 0; g < 4; ++g) S[rg][s][g] = 0.f;
#pragma unroll
        for (int s = 0; s < 4; ++s)
#pragma unroll
            for (int c2 = 0; c2 < 2; ++c2) {
                v8s kb = *(const v8s*)&Kl[cur][s * 16 + c15][((c2 * 4 + quad) ^ r7) * 8];
                S[0][s] = mfma16(Qa[0][c2], kb, S[0][s]);
                S[1][s] = mfma16(Qa[1][c2], kb, S[1][s]);
            }

        // fixed-max softmax: P = 2^s ; swizzled packed writes
#pragma unroll
        for (int rg = 0; rg < 2; ++rg) {
            float E[4][4];
#pragma unroll
            for (int s = 0; s < 4; ++s)
#pragma unroll
                for (int g = 0; g < 4; ++g) {
                    float e = fexp2(S[rg][s][g]);
                    E[s][g] = e;
                    ls[rg][g] += e;
                }
#pragma unroll
            for (int g = 0; g < 4; ++g) {
                int row = rg * 16 + quad * 4 + g;
                union { u16x4 v; u32 w[2]; } p2;
                p2.w[0] = pkbf(E[0][g], E[1][g]);
                p2.w[1] = pkbf(E[2][g], E[3][g]);
                // pos c15*4..+3 -> chunk c15>>1 (swizzled), half c15&1
                *(u16x4*)&Pl[wv][row][(((c15 >> 1) ^ (row & 7)) * 8) + (c15 & 1) * 4] = p2.v;
            }
        }
        // per-wave Pl round-trip: lgkmcnt orders intra-wave

        v8s Pa[2][2];
#pragma unroll
        for (int rg = 0; rg < 2; ++rg)
#pragma unroll
            for (int c2 = 0; c2 < 2; ++c2)
                Pa[rg][c2] = *(const v8s*)&Pl[wv][rg * 16 + c15][((c2 * 4 + quad) ^ r7) * 8];

        // wait own V DMA (K(i+1) stays in flight), raw barrier for cross-wave V
        asm volatile("s_waitcnt vmcnt(2)\n\ts_barrier" ::: "memory");

        // O += P V from Vl
#pragma unroll
        for (int cg = 0; cg < 4; ++cg)
#pragma unroll
            for (int c2 = 0; c2 < 2; ++c2) {
                v8s vb = *(const v8s*)&Vl[cg * 16 + c15][((c2 * 4 + quad) ^ r7) * 8];
                O[0][cg] = mfma16(Pa[0][c2], vb, O[0][cg]);
                O[1][cg] = mfma16(Pa[1][c2], vb, O[1][cg]);
            }
        __syncthreads();   // drain (covers K(i+1)); protects Vl/Kl for next iter
    }

    u16* OPp = OP + (size_t)p * (NB * NN * 64) + (size_t)b * NN * 64;
#pragma unroll
    for (int rg = 0; rg < 2; ++rg)
#pragma unroll
        for (int cg = 0; cg < 4; ++cg)
#pragma unroll
            for (int g = 0; g < 4; ++g) {
                int n = nw + rg * 16 + quad * 4 + g;
                OPp[(size_t)n * 64 + cg * 16 + c15] = f2bf(O[rg][cg][g]);
            }
#pragma unroll
    for (int rg = 0; rg < 2; ++rg)
#pragma unroll
        for (int g = 0; g < 4; ++g) {
            float v = ls[rg][g];
#pragma unroll
            for (int off = 1; off <= 8; off <<= 1) v += __shfl_xor(v, off);
            ls[rg][g] = v;
        }
    if (c15 == 0) {
        float* Lp = Lb + (size_t)p * (NB * NN) + (size_t)b * NN;
#pragma unroll
        for (int rg = 0; rg < 2; ++rg)
#pragma unroll
            for (int g = 0; g < 4; ++g) {
                int n = nw + rg * 16 + quad * 4 + g;
                Lp[n] = ls[rg][g];
            }
    }
}

// ------------- kernel 3: merge splits + Wp MFMA projection + residual -------
#define OMP 72
__global__ __launch_bounds__(256) void k_proj(const u16* __restrict__ OP,
                                              const float* __restrict__ Lb,
                                              const float* __restrict__ Wp,
                                              const float* __restrict__ x,
                                              float* __restrict__ out,
                                              int nsp) {
    __shared__ u16 Om[16 * OMP];
    int t = threadIdx.x;
    int b = blockIdx.x >> 8;
    int n0 = (blockIdx.x & 255) * 16;

    {
        int n_l = t >> 4, r0 = (t & 15) * 4;
        size_t nidx = (size_t)b * NN + n0 + n_l;
        float o[4] = {0.f, 0.f, 0.f, 0.f};
        float l = 0.f;
        for (int p = 0; p < nsp; ++p) {
            u16x4 u = *(const u16x4*)&OP[((size_t)p * (NB * NN) + nidx) * 64 + r0];
#pragma unroll
            for (int j = 0; j < 4; ++j) o[j] += bf2f(u[j]);
            l += Lb[(size_t)p * (NB * NN) + nidx];
        }
        float inv = 1.0f / l;
        union { u16x4 v; u32 w[2]; } p2;
        p2.w[0] = pkbf(o[0] * inv, o[1] * inv);
        p2.w[1] = pkbf(o[2] * inv, o[3] * inv);
        *(u16x4*)&Om[n_l * OMP + r0] = p2.v;
    }
    __syncthreads();

    int lane = t & 63, wvv = t >> 6, c15 = lane & 15, quad = lane >> 4;
    v8s B0 = *(const v8s*)&Om[c15 * OMP + quad * 8];
    v8s B1 = *(const v8s*)&Om[c15 * OMP + 32 + quad * 8];
#pragma unroll
    for (int ct0 = 0; ct0 < 4; ++ct0) {
        int ct = wvv * 4 + ct0;
        // inline fp32 Wp -> bf16 A-frags: A[m=cout][k=r]
        const float* wr = Wp + (size_t)(ct * 16 + c15) * 64 + quad * 8;
        float4 wa = *(const float4*)&wr[0];
        float4 wb = *(const float4*)&wr[4];
        float4 wc = *(const float4*)&wr[32];
        float4 wd = *(const float4*)&wr[36];
        union { v8s s; u32 w[4]; } pa, pb;
        pa.w[0] = pkbf(wa.x, wa.y); pa.w[1] = pkbf(wa.z, wa.w);
        pa.w[2] = pkbf(wb.x, wb.y); pa.w[3] = pkbf(wb.z, wb.w);
        pb.w[0] = pkbf(wc.x, wc.y); pb.w[1] = pkbf(wc.z, wc.w);
        pb.w[2] = pkbf(wd.x, wd.y); pb.w[3] = pkbf(wd.z, wd.w);
        v4f acc = {0.f, 0.f, 0.f, 0.f};
        acc = mfma16(pa.s, B0, acc);
        acc = mfma16(pb.s, B1, acc);
        size_t base = ((size_t)(b * 256 + ct * 16 + quad * 4)) * 4096 + n0 + c15;
#pragma unroll
        for (int g = 0; g < 4; ++g)
            out[base + (size_t)g * 4096] = acc[g] + x[base + (size_t)g * 4096];
    }
}

extern "C" void kernel_launch(void* const* d_in, const int* in_sizes, int n_in,
                              void* d_out, int out_size, void* d_ws, size_t ws_size,
                              hipStream_t stream) {
    const float* x  = (const float*)d_in[0];
    const float* Wq = (const float*)d_in[1];
    const float* Wk = (const float*)d_in[2];
    const float* Wv = (const float*)d_in[3];
    const float* Wp = (const float*)d_in[4];
    float* out = (float*)d_out;
    char* ws = (char*)d_ws;

    int nsp = (ws_size >= (size_t)24 * 1024 * 1024) ? 8 : 4;
    int sh = (nsp == 8) ? 3 : 2;

    u16* Q   = (u16*)(ws);                                   // 2 MB
    u16* K   = (u16*)(ws + 2097152);                         // 2 MB
    u16* V   = (u16*)(ws + 2 * 2097152);                     // 2 MB
    u16* OP  = (u16*)(ws + 3 * 2097152);                     // nsp*2 MB
    float* Lbuf = (float*)(ws + (size_t)(3 + nsp) * 2097152);

    k_qkvm<<<512, 256, 0, stream>>>(x, Wq, Wk, Wv, Q, K, V);
    k_flash<<<NB * 32 * nsp, 256, 0, stream>>>(Q, K, V, OP, Lbuf, sh);
    k_proj<<<NB * 256, 256, 0, stream>>>(OP, Lbuf, Wp, x, out, nsp);
}